// Round 5
// baseline (206.631 us; speedup 1.0000x reference)
//
#include <hip/hip_runtime.h>
#include <hip/hip_bf16.h>

// Problem constants
#define B_   8
#define S_   1024
#define D_   768
#define H_   16
#define PD_  48
#define PDP  64        // padded per-head dim
#define M_   8192      // B*S
#define BH_  128       // B*H

// 1/sqrt(48) * log2(e)  -> folded into Q so softmax is a bare exp2
#define QSCALE 0.20823031f

typedef __attribute__((ext_vector_type(8))) short short8;
typedef __attribute__((ext_vector_type(4))) float floatx4;

// bf16 round-half-up: same |err| bound as RNE (differs only on exact ties).
__device__ __forceinline__ unsigned short f2bf(float f) {
    return (unsigned short)((__float_as_uint(f) + 0x8000u) >> 16);
}
// pack two floats -> (bf16(hi)<<16)|bf16(lo) : 2 adds + 1 v_perm
__device__ __forceinline__ unsigned int pack_bf2(float lo, float hi) {
    unsigned a = __float_as_uint(hi) + 0x8000u;
    unsigned b = __float_as_uint(lo) + 0x8000u;
    return __builtin_amdgcn_perm(a, b, 0x07060302u);
}

// async 16B global -> LDS (direct, no VGPR round trip). LDS dest must be
// wave-uniform base + lane*16; any swizzle must be folded into the GLOBAL addr.
__device__ __forceinline__ void async_copy16(const unsigned short* gptr, unsigned short* lptr) {
    __builtin_amdgcn_global_load_lds(
        (const __attribute__((address_space(1))) unsigned int*)gptr,
        (__attribute__((address_space(3))) unsigned int*)lptr, 16, 0, 0);
}

// ---------------------------------------- fused: convert X + transpose weights
// blocks [0,6144): cast X tile to bf16. blocks [6144,8448): W transpose+cast.
__global__ __launch_bounds__(256) void prep_kernel(
    const float* __restrict__ X, unsigned short* __restrict__ Xb,
    const float* __restrict__ w0, const float* __restrict__ w1,
    const float* __restrict__ w2, const float* __restrict__ w3,
    unsigned short* __restrict__ Wtall) {
    __shared__ float tile[32][33];
    const int tid = threadIdx.x;
    const int bx = blockIdx.x;
    if (bx < 6144) {
        long i = ((long)bx * 256 + tid) * 4;
        float4 v = *(const float4*)(X + i);
        uint2 o;
        o.x = pack_bf2(v.x, v.y);
        o.y = pack_bf2(v.z, v.w);
        *(uint2*)(Xb + i) = o;
        return;
    }
    const int t = bx - 6144;
    const int z = t / 576, r = t % 576;
    const int nt = (r % 24) * 32, kt = (r / 24) * 32;
    const int tx = tid & 31, ty = tid >> 5;
    const float* W = (z == 0) ? w0 : (z == 1) ? w1 : (z == 2) ? w2 : w3;
    unsigned short* Wt = Wtall + (long)z * D_ * D_;
#pragma unroll
    for (int i = 0; i < 4; i++)
        tile[ty + i * 8][tx] = W[(long)(kt + ty + i * 8) * D_ + nt + tx];
    __syncthreads();
#pragma unroll
    for (int i = 0; i < 4; i++)
        Wt[(long)(nt + ty + i * 8) * D_ + kt + tx] = f2bf(tile[tx][ty + i * 8]);
}

// --------------------------------------------------------------- GEMM core
// C[128x128] = A[128xK] * Bt[128xK]^T, bf16 in, fp32 acc.
// LDS XOR-swizzle: LDS chunk (row, seg_sw) holds global seg = seg_sw ^ (row&7).
__device__ __forceinline__ void gemm_core(
    const unsigned short* __restrict__ Ag,   // A rows at m0, stride D_
    const unsigned short* __restrict__ Btg,  // Bt rows at n0, stride D_
    unsigned short* Asm, unsigned short* Bsm, floatx4 acc[4][4]) {
    const int tid = threadIdx.x;
    const int lane = tid & 63, w = tid >> 6;
    const int wr = (w >> 1) * 64, wc = (w & 1) * 64;
    const int l15 = lane & 15, l4 = lane >> 4;
    const floatx4 zero = {0.f, 0.f, 0.f, 0.f};
#pragma unroll
    for (int mt = 0; mt < 4; mt++)
#pragma unroll
        for (int nt = 0; nt < 4; nt++) acc[mt][nt] = zero;

    for (int kb = 0; kb < D_; kb += 64) {
#pragma unroll
        for (int i = 0; i < 4; i++) {
            int c = tid + i * 256;
            int row = c >> 3, seg = (c & 7) ^ (row & 7);
            long goff = (long)row * D_ + kb + seg * 8;
            async_copy16(&Ag[goff], &Asm[c * 8]);
            async_copy16(&Btg[goff], &Bsm[c * 8]);
        }
        __syncthreads();
#pragma unroll
        for (int kk = 0; kk < 2; kk++) {
            short8 af[4], bf[4];
#pragma unroll
            for (int mt = 0; mt < 4; mt++) {
                int r = wr + mt * 16 + l15;
                af[mt] = *(const short8*)&Asm[r * 64 + (((kk * 4 + l4) ^ (r & 7)) * 8)];
            }
#pragma unroll
            for (int nt = 0; nt < 4; nt++) {
                int c = wc + nt * 16 + l15;
                bf[nt] = *(const short8*)&Bsm[c * 64 + (((kk * 4 + l4) ^ (c & 7)) * 8)];
            }
#pragma unroll
            for (int mt = 0; mt < 4; mt++)
#pragma unroll
                for (int nt = 0; nt < 4; nt++)
                    acc[mt][nt] = __builtin_amdgcn_mfma_f32_16x16x32_bf16(
                        af[mt], bf[nt], acc[mt][nt], 0, 0, 0);
        }
        __syncthreads();
    }
}

// ------------------------------------------------------- QKV projection GEMM
// Grid: x = m-block (64), y = n-block (6), z = Q/K/V. m-major => per-XCD L2
// pins A-tiles. z=0/1 (Q/K): [bh][s][64] layout (pads unwritten; Q pad zeroed
// in-register by attn; K pad multiplied by that zero).
// z=2 (V): writes V^T [bh][64][s] directly (r packs 4 consecutive s) + the
// ones-row at d=48 (l-accumulator column). Rows 49..63 stay garbage: only the
// l15==0 column of accO[3] is ever read, and it touches row 48 only.
__global__ __launch_bounds__(256) void gemm_qkv_kernel(
    const unsigned short* __restrict__ Xb, const unsigned short* __restrict__ Wtall,
    const float* __restrict__ bq, const float* __restrict__ bk,
    const float* __restrict__ bv, unsigned short* __restrict__ QK,
    unsigned short* __restrict__ Vt) {
    __shared__ __align__(16) unsigned short Asm[128 * 64];
    __shared__ __align__(16) unsigned short Bsm[128 * 64];
    const int z = blockIdx.z;
    const int m0 = blockIdx.x * 128, n0 = blockIdx.y * 128;
    const float* bias = (z == 0) ? bq : (z == 1) ? bk : bv;
    const float vscale = (z == 0) ? QSCALE : 1.0f;
    floatx4 acc[4][4];
    gemm_core(Xb + (long)m0 * D_, Wtall + (long)z * D_ * D_ + (long)n0 * D_, Asm, Bsm, acc);

    const int tid = threadIdx.x, lane = tid & 63, w = tid >> 6;
    const int wr = (w >> 1) * 64, wc = (w & 1) * 64;
    const int l15 = lane & 15, l4 = lane >> 4;
    const int b = m0 >> 10, sbase = m0 & 1023;

    if (z == 2) {
        // V^T data
#pragma unroll
        for (int nt = 0; nt < 4; nt++) {
            int n = n0 + wc + nt * 16 + l15;
            int h = n / PD_, pd = n % PD_;
            float bb = bias[n];
            long rowbase = ((long)(b * H_ + h) * PDP + pd) * S_;
#pragma unroll
            for (int mt = 0; mt < 4; mt++) {
                uint2 pp;
                pp.x = pack_bf2(acc[mt][nt][0] + bb, acc[mt][nt][1] + bb);
                pp.y = pack_bf2(acc[mt][nt][2] + bb, acc[mt][nt][3] + bb);
                int s = sbase + wr + mt * 16 + l4 * 4;
                *(uint2*)&Vt[rowbase + s] = pp;
            }
        }
        // ones-row d=48 for heads covered by this n-block (idempotent overlap)
        const int h0 = n0 / PD_, h1 = (n0 + 127) / PD_;
        if (tid < 32) {
            const uint2 ones = {0x3F803F80u, 0x3F803F80u};
            for (int h = h0; h <= h1; h++) {
                long off = ((long)(b * H_ + h) * PDP + PD_) * S_ + sbase + tid * 4;
                *(uint2*)&Vt[off] = ones;
            }
        }
        return;
    }

    unsigned short* out = QK + (long)z * BH_ * S_ * PDP;
#pragma unroll
    for (int nt = 0; nt < 4; nt++) {
        int n = n0 + wc + nt * 16 + l15;
        int h = n / PD_, pd = n % PD_;
        float bb = bias[n];
#pragma unroll
        for (int mt = 0; mt < 4; mt++) {
#pragma unroll
            for (int r = 0; r < 4; r++) {
                int s = sbase + wr + mt * 16 + l4 * 4 + r;
                out[((long)(b * H_ + h) * S_ + s) * PDP + pd] = f2bf((acc[mt][nt][r] + bb) * vscale);
            }
        }
    }
}

// --------------------------------------------------------- output projection
__global__ __launch_bounds__(256) void gemm_out_kernel(
    const unsigned short* __restrict__ Ctx, const unsigned short* __restrict__ Wot,
    const float* __restrict__ bo, float* __restrict__ Out) {
    __shared__ __align__(16) unsigned short Asm[128 * 64];
    __shared__ __align__(16) unsigned short Bsm[128 * 64];
    const int m0 = blockIdx.x * 128, n0 = blockIdx.y * 128;
    floatx4 acc[4][4];
    gemm_core(Ctx + (long)m0 * D_, Wot + (long)n0 * D_, Asm, Bsm, acc);

    const int tid = threadIdx.x, lane = tid & 63, w = tid >> 6;
    const int wr = (w >> 1) * 64, wc = (w & 1) * 64;
    const int l15 = lane & 15, l4 = lane >> 4;
#pragma unroll
    for (int nt = 0; nt < 4; nt++) {
        int n = n0 + wc + nt * 16 + l15;
        float bb = bo[n];
#pragma unroll
        for (int mt = 0; mt < 4; mt++) {
#pragma unroll
            for (int r = 0; r < 4; r++) {
                int m = m0 + wr + mt * 16 + l4 * 4 + r;
                Out[(long)m * D_ + n] = acc[mt][nt][r] + bb;
            }
        }
    }
}

// ------------------------------------------------------------ flash attention
// One block = (b,h) x 256-query tile; 4 waves x 64 queries (4 groups of 16).
// Grid: x = bh (128), y = qt (4) => all qt-blocks of a bh share an XCD L2.
// S^T = K*Q^T; fixed-max softmax P = exp2 (scale*log2e folded into Q).
// Q pad (d>=48) zeroed IN-REGISTER. l via ones-column at V^T row d=48.
__global__ __launch_bounds__(256) void attn_kernel(
    const unsigned short* __restrict__ Qg, const unsigned short* __restrict__ Kg,
    const unsigned short* __restrict__ Vtg, unsigned short* __restrict__ Ctx) {
    __shared__ __align__(16) unsigned short Ks[64 * 64];    // [key][d] swizzled
    __shared__ __align__(16) unsigned short Vs[64 * 64];    // [d][key] swizzled
    __shared__ __align__(16) unsigned short Ps[4][64 * 64]; // per-wave [q][key] swizzled
    const int tid = threadIdx.x, lane = tid & 63, w = tid >> 6;
    const int l15 = lane & 15, l4 = lane >> 4;
    const int bh = blockIdx.x, qt = blockIdx.y;
    const long qkbase = (long)bh * S_ * PDP;   // Q/K: [bh][s][64]
    const long vbase  = (long)bh * PDP * S_;   // Vt:  [bh][d][1024]

    // Q B-fragments from global; wave w owns queries w*64..w*64+63
    short8 bq[4][2];
#pragma unroll
    for (int g = 0; g < 4; g++) {
        int qrow = qt * 256 + w * 64 + g * 16 + l15;
        bq[g][0] = *(const short8*)&Qg[qkbase + (long)qrow * PDP + l4 * 8];
        bq[g][1] = *(const short8*)&Qg[qkbase + (long)qrow * PDP + 32 + l4 * 8];
    }
    if (l4 >= 2) {   // zero Q pad d=48..63 (chunk1 lanes l4=2,3 hold k=48..63)
        const short8 z8 = {0, 0, 0, 0, 0, 0, 0, 0};
#pragma unroll
        for (int g = 0; g < 4; g++) bq[g][1] = z8;
    }

    const floatx4 zero = {0.f, 0.f, 0.f, 0.f};
    floatx4 accO[4][4];
#pragma unroll
    for (int g = 0; g < 4; g++)
#pragma unroll
        for (int nt = 0; nt < 4; nt++) accO[g][nt] = zero;

    unsigned short* Pw = &Ps[w][0];

    for (int kt = 0; kt < 16; kt++) {
        __syncthreads();
        // stage K [key][d] and V^T [d][key] tiles: 8KB each, direct-to-LDS
#pragma unroll
        for (int i = 0; i < 2; i++) {
            int c = tid + i * 256;
            int row = c >> 3, seg = (c & 7) ^ (row & 7);
            async_copy16(&Kg[qkbase + (long)(kt * 64 + row) * PDP + seg * 8], &Ks[c * 8]);
            async_copy16(&Vtg[vbase + (long)row * S_ + kt * 64 + seg * 8], &Vs[c * 8]);
        }
        __syncthreads();

        // K A-frags, shared across all 4 query groups
        short8 ak[4][2];
#pragma unroll
        for (int ks = 0; ks < 4; ks++) {
            int kr = ks * 16 + l15;
            ak[ks][0] = *(const short8*)&Ks[kr * 64 + ((l4 ^ (kr & 7)) * 8)];
            ak[ks][1] = *(const short8*)&Ks[kr * 64 + (((4 + l4) ^ (kr & 7)) * 8)];
        }

        // scores + P for all groups
#pragma unroll
        for (int g = 0; g < 4; g++) {
            floatx4 sc[4];
#pragma unroll
            for (int ks = 0; ks < 4; ks++) {
                floatx4 a = zero;
                a = __builtin_amdgcn_mfma_f32_16x16x32_bf16(ak[ks][0], bq[g][0], a, 0, 0, 0);
                a = __builtin_amdgcn_mfma_f32_16x16x32_bf16(ak[ks][1], bq[g][1], a, 0, 0, 0);
                sc[ks] = a;
            }
            int prow = g * 16 + l15;
#pragma unroll
            for (int ks = 0; ks < 4; ks++) {
                uint2 pp;
                pp.x = pack_bf2(__builtin_amdgcn_exp2f(sc[ks][0]),
                                __builtin_amdgcn_exp2f(sc[ks][1]));
                pp.y = pack_bf2(__builtin_amdgcn_exp2f(sc[ks][2]),
                                __builtin_amdgcn_exp2f(sc[ks][3]));
                int addr = prow * 64 + (((ks * 2 + (l4 >> 1)) ^ (prow & 7)) * 8) + (l4 & 1) * 4;
                *(uint2*)&Pw[addr] = pp;
            }
        }

        // PV: V B-frags hoisted per kk, shared across groups
#pragma unroll
        for (int kk = 0; kk < 2; kk++) {
            short8 bv[4];
#pragma unroll
            for (int nt = 0; nt < 4; nt++) {
                int vr = nt * 16 + l15;
                bv[nt] = *(const short8*)&Vs[vr * 64 + (((kk * 4 + l4) ^ (vr & 7)) * 8)];
            }
#pragma unroll
            for (int g = 0; g < 4; g++) {
                int prow = g * 16 + l15;
                short8 ap = *(const short8*)&Pw[prow * 64 + (((kk * 4 + l4) ^ (prow & 7)) * 8)];
#pragma unroll
                for (int nt = 0; nt < 4; nt++)
                    accO[g][nt] = __builtin_amdgcn_mfma_f32_16x16x32_bf16(ap, bv[nt], accO[g][nt], 0, 0, 0);
            }
        }
    }

    // epilogue: l = accO[g][3] at l15==0 (d=48 ones-column); out = accO/l
    const int b = bh >> 4, h = bh & 15;
#pragma unroll
    for (int g = 0; g < 4; g++) {
#pragma unroll
        for (int r = 0; r < 4; r++) {
            float lsum = __shfl(accO[g][3][r], lane & 48);
            float inv = 1.0f / lsum;
            int q = qt * 256 + w * 64 + g * 16 + l4 * 4 + r;
            long rowoff = (long)(b * S_ + q) * D_ + h * PD_;
#pragma unroll
            for (int nt = 0; nt < 3; nt++)
                Ctx[rowoff + nt * 16 + l15] = f2bf(accO[g][nt][r] * inv);
        }
    }
}

// ---------------------------------------------------------------------------
extern "C" void kernel_launch(void* const* d_in, const int* in_sizes, int n_in,
                              void* d_out, int out_size, void* d_ws, size_t ws_size,
                              hipStream_t stream) {
    const float* X  = (const float*)d_in[0];
    const float* Wq = (const float*)d_in[1];
    const float* bq = (const float*)d_in[2];
    const float* Wk = (const float*)d_in[3];
    const float* bk = (const float*)d_in[4];
    const float* Wv = (const float*)d_in[5];
    const float* bv = (const float*)d_in[6];
    const float* Wo = (const float*)d_in[7];
    const float* bo = (const float*)d_in[8];

    unsigned char* ws = (unsigned char*)d_ws;
    const long XB_BYTES  = (long)M_ * D_ * 2;         // 12,582,912
    const long WT_BYTES  = (long)D_ * D_ * 2;         // 1,179,648
    const long QKV_BYTES = (long)BH_ * S_ * PDP * 2;  // 16,777,216

    unsigned short* Xbf   = (unsigned short*)(ws);
    unsigned short* Wtall = (unsigned short*)(ws + XB_BYTES);
    unsigned short* QKws  = (unsigned short*)(ws + XB_BYTES + 4 * WT_BYTES);
    unsigned short* Vtws  = QKws + 2 * (QKV_BYTES / 2);
    unsigned short* Ctx   = Vtws + QKV_BYTES / 2;

    prep_kernel<<<8448, 256, 0, stream>>>(X, Xbf, Wq, Wk, Wv, Wo, Wtall);
    gemm_qkv_kernel<<<dim3(64, 6, 3), 256, 0, stream>>>(Xbf, Wtall, bq, bk, bv, QKws, Vtws);
    attn_kernel<<<dim3(128, 4), 256, 0, stream>>>(QKws, QKws + QKV_BYTES / 2, Vtws, Ctx);
    gemm_out_kernel<<<dim3(64, 6), 256, 0, stream>>>(
        Ctx, Wtall + 3 * (WT_BYTES / 2), bo, (float*)d_out);
}